// Round 3
// baseline (3671.062 us; speedup 1.0000x reference)
//
#include <hip/hip_runtime.h>
#include <stdint.h>

#define TT 512
#define BB 256
#define HH 512
#define NOUTC 64
// 16 groups x 16 blocks. R9: wave-autonomous pipeline — each wave polls all
// 64 group flags and loads its MFMA B-fragments (h_{t-1}) DIRECTLY from
// global h_buf via agent-scope 8B atomic loads (no LDS h-staging, no B1/B2).
// One barrier per step (orders double-buffered x LDS writes). Classifier
// reuses the retained B-fragments in registers (zero loads, no races).

typedef _Float16 f16;
typedef f16 f16x8 __attribute__((ext_vector_type(8)));
typedef float f32x4 __attribute__((ext_vector_type(4)));
typedef unsigned long long ull;

__device__ __forceinline__ float sigmoidf_(float x) {
  x = fminf(fmaxf(x, -30.f), 30.f);
  return 1.f / (1.f + __expf(-x));
}
__device__ __forceinline__ float tanhf_(float x) {
  x = fminf(fmaxf(x, -15.f), 15.f);
  float e = __expf(2.f * x);
  return (e - 1.f) / (e + 1.f);
}

__device__ __forceinline__ f16x8 cvt8(const float* __restrict__ src) {
  float4 p0 = *(const float4*)(src);
  float4 p1 = *(const float4*)(src + 4);
  f16x8 a;
  a[0] = (f16)p0.x; a[1] = (f16)p0.y; a[2] = (f16)p0.z; a[3] = (f16)p0.w;
  a[4] = (f16)p1.x; a[5] = (f16)p1.y; a[6] = (f16)p1.z; a[7] = (f16)p1.w;
  return a;
}

__global__ void zero_ws(uint32_t* __restrict__ ws, int nws) {
  int idx = blockIdx.x * blockDim.x + threadIdx.x;
  int stride = gridDim.x * blockDim.x;
  for (int i = idx; i < nws; i += stride) ws[i] = 0u;
}

__global__ __launch_bounds__(256, 1) void lstm_kernel(
    const float* __restrict__ input, const float* __restrict__ dtp,
    const float* __restrict__ W_ih, const float* __restrict__ W_hh,
    const float* __restrict__ b_ih, const float* __restrict__ b_hh,
    const float* __restrict__ W_cls, const float* __restrict__ b_cls,
    float* __restrict__ out, uint32_t* __restrict__ flg,
    f16* __restrict__ h_buf) {
  __shared__ __align__(16) f16 xb[2][16][136];   // x double-buffer, padded
  __shared__ __align__(16) f16x8 wlds[16][64];   // W_cls frags (cls blocks)

  const int tid = threadIdx.x;
  const int g = blockIdx.x & 15;   // group: batch slice [g*16, g*16+16)
  const int s = blockIdx.x >> 4;   // sub: hidden slice [s*32, s*32+32)
  const int b0 = g * 16;
  const int w = tid >> 6;          // wave id 0..3
  const int lane = tid & 63;
  const int l = lane & 15;
  const int quad = lane >> 4;
  const int mt_o = s & 3;
  const bool cls_block = (s < 4);
  const int hb = s * 32 + w * 8;   // wave's 8-hidden slice base

  // ---- A-fragments: m-tile0 rows = {i,f}x8h, m-tile1 = {g,o}x8h.
  // D mapping: m=quad*4+r -> gate m>>3, h = hb + (m&7); col n = l.
  f16x8 afrag[2][20];
#pragma unroll
  for (int mp = 0; mp < 2; ++mp) {
    const int grow = (mp * 2 + (l >> 3)) * HH + hb + (l & 7);
#pragma unroll
    for (int it = 0; it < 20; ++it) {
      const int kb = it * 32 + quad * 8;
      const float* src = (kb < 128) ? (W_ih + (size_t)grow * 128 + kb)
                                    : (W_hh + (size_t)grow * HH + (kb - 128));
      afrag[mp][it] = cvt8(src);
    }
  }

  // ---- gate biases (quad<2 lanes): h = hb + (quad&1)*4 + r
  float gb_i[4], gb_f[4], gb_g[4], gb_o[4];
  {
    const int hg = hb + (quad & 1) * 4;
#pragma unroll
    for (int r = 0; r < 4; ++r) {
      gb_i[r] = b_ih[0 * HH + hg + r] + b_hh[0 * HH + hg + r];
      gb_f[r] = b_ih[1 * HH + hg + r] + b_hh[1 * HH + hg + r];
      gb_g[r] = b_ih[2 * HH + hg + r] + b_hh[2 * HH + hg + r];
      gb_o[r] = b_ih[3 * HH + hg + r] + b_hh[3 * HH + hg + r];
    }
  }

  // ---- classifier state (wave0 of s<4 blocks)
  float bcls4[4] = {0.f, 0.f, 0.f, 0.f};
  if (cls_block && w == 0) {
#pragma unroll
    for (int r = 0; r < 4; ++r) bcls4[r] = b_cls[mt_o * 16 + quad * 4 + r];
#pragma unroll
    for (int it = 0; it < 16; ++it)
      wlds[it][lane] =
          cvt8(W_cls + (size_t)(mt_o * 16 + l) * HH + it * 32 + quad * 8);
  }

  // classify from register-retained B-fragments (h rows n=l)
  auto classify = [&](const f16x8* bfr, int tt) {
    f32x4 oa = {0.f, 0.f, 0.f, 0.f}, ob = {0.f, 0.f, 0.f, 0.f};
#pragma unroll
    for (int it = 0; it < 16; it += 2) {
      oa = __builtin_amdgcn_mfma_f32_16x16x32_f16(wlds[it][lane], bfr[it], oa, 0, 0, 0);
      ob = __builtin_amdgcn_mfma_f32_16x16x32_f16(wlds[it + 1][lane], bfr[it + 1], ob, 0, 0, 0);
    }
    float4 o;
    o.x = oa[0] + ob[0] + bcls4[0];
    o.y = oa[1] + ob[1] + bcls4[1];
    o.z = oa[2] + ob[2] + bcls4[2];
    o.w = oa[3] + ob[3] + bcls4[3];
    *(float4*)(out + ((size_t)tt * BB + b0 + l) * NOUTC + mt_o * 16 +
               quad * 4) = o;
  };

  // ---- prologue: stage x_0 into slot 0
  const int kx = tid & 127;
  const int nx0 = tid >> 7;
#pragma unroll
  for (int ii = 0; ii < 8; ++ii) {
    const int row = b0 + ii * 2 + nx0;
    float v = (kx < 127) ? input[(size_t)row * 127 + kx] : dtp[row];
    xb[0][ii * 2 + nx0][kx] = (f16)v;
  }
  float cc[4] = {0.f, 0.f, 0.f, 0.f};
  __syncthreads();

  const uint32_t* fpoll = flg + (size_t)(g * 64 + lane) * 4;

  for (int t = 0; t < TT; ++t) {
    // ---- every wave polls all 64 group flags (h_{t-1} published everywhere)
    for (;;) {
      uint32_t v = __hip_atomic_load(fpoll, __ATOMIC_RELAXED,
                                     __HIP_MEMORY_SCOPE_AGENT);
      if (__ballot(v >= (uint32_t)t) == ~0ull) break;
      __builtin_amdgcn_s_sleep(1);
    }
    asm volatile("" ::: "memory");  // no reordering of loads above the poll

    // ---- B-fragments: h_{t-1} row l, cols kk*32+quad*8..+8, direct global
    f16x8 bfr[16];
    {
      const ull* hp = (const ull*)h_buf +
                      (size_t)((((t + 1) & 1) * 16) + g) * 2048 + l * 128 +
                      quad * 2;
#pragma unroll
      for (int kk = 0; kk < 16; ++kk) {
        ull lo = __hip_atomic_load(hp + kk * 8, __ATOMIC_RELAXED,
                                   __HIP_MEMORY_SCOPE_AGENT);
        ull hi = __hip_atomic_load(hp + kk * 8 + 1, __ATOMIC_RELAXED,
                                   __HIP_MEMORY_SCOPE_AGENT);
        union { ull u2[2]; f16x8 v8; } cv;
        cv.u2[0] = lo; cv.u2[1] = hi;
        bfr[kk] = cv.v8;
      }
    }

    // ---- gates: x-part from LDS (4 chunks), h-part from bfr (16 chunks)
    f32x4 acc0 = {0.f, 0.f, 0.f, 0.f}, acc1 = {0.f, 0.f, 0.f, 0.f};
    const int xs = t & 1;
#pragma unroll
    for (int it = 0; it < 4; ++it) {
      f16x8 b = *(const f16x8*)(&xb[xs][l][it * 32 + quad * 8]);
      acc0 = __builtin_amdgcn_mfma_f32_16x16x32_f16(afrag[0][it], b, acc0, 0, 0, 0);
      acc1 = __builtin_amdgcn_mfma_f32_16x16x32_f16(afrag[1][it], b, acc1, 0, 0, 0);
    }
#pragma unroll
    for (int kk = 0; kk < 16; ++kk) {
      acc0 = __builtin_amdgcn_mfma_f32_16x16x32_f16(afrag[0][4 + kk], bfr[kk], acc0, 0, 0, 0);
      acc1 = __builtin_amdgcn_mfma_f32_16x16x32_f16(afrag[1][4 + kk], bfr[kk], acc1, 0, 0, 0);
    }

    // ---- cell update in regs; f,o come from lane^32
    float fsh[4], osh[4];
#pragma unroll
    for (int r = 0; r < 4; ++r) {
      fsh[r] = __shfl_xor(acc0[r], 32, 64);
      osh[r] = __shfl_xor(acc1[r], 32, 64);
    }
    if (quad < 2) {
      union { f16 h4[4]; ull u; } pk;
#pragma unroll
      for (int r = 0; r < 4; ++r) {
        float vi = acc0[r] + gb_i[r];
        float vf = fsh[r] + gb_f[r];
        float vg = acc1[r] + gb_g[r];
        float vo = osh[r] + gb_o[r];
        float iv = sigmoidf_(vi), fv = sigmoidf_(vf);
        float gv = tanhf_(vg), ov = sigmoidf_(vo);
        cc[r] = fv * cc[r] + iv * gv;
        pk.h4[r] = (f16)(ov * tanhf_(cc[r]));
      }
      __hip_atomic_store(
          (ull*)(h_buf + (size_t)(((t & 1) * 16) + g) * (16 * HH) +
                 (size_t)l * HH + hb + quad * 4),
          pk.u, __ATOMIC_RELAXED, __HIP_MEMORY_SCOPE_AGENT);
    }
    // wave-local drain of the publish, then this wave's flag
    asm volatile("s_waitcnt vmcnt(0)" ::: "memory");
    if (lane == 0)
      __hip_atomic_store(flg + (size_t)(g * 64 + s * 4 + w) * 4,
                         (uint32_t)(t + 1), __ATOMIC_RELAXED,
                         __HIP_MEMORY_SCOPE_AGENT);

    // ---- classifier out[t-1] from retained bfr (off critical path)
    if (t > 0 && cls_block && w == 0) classify(bfr, t - 1);

    // ---- x_{t+1} into the other slot
    if (t + 1 < TT) {
#pragma unroll
      for (int ii = 0; ii < 8; ++ii) {
        const int row = (t + 1) * BB + b0 + ii * 2 + nx0;
        float v = (kx < 127) ? input[(size_t)row * 127 + kx] : dtp[row];
        xb[xs ^ 1][ii * 2 + nx0][kx] = (f16)v;
      }
    }
    __syncthreads();  // the one barrier: orders x writes for next iter
  }

  // ---- final output row uses h_{TT-1}
  if (cls_block && w == 0) {
    for (;;) {
      uint32_t v = __hip_atomic_load(fpoll, __ATOMIC_RELAXED,
                                     __HIP_MEMORY_SCOPE_AGENT);
      if (__ballot(v >= (uint32_t)TT) == ~0ull) break;
      __builtin_amdgcn_s_sleep(1);
    }
    asm volatile("" ::: "memory");
    f16x8 bfr[16];
    const ull* hp = (const ull*)h_buf +
                    (size_t)((((TT + 1) & 1) * 16) + g) * 2048 + l * 128 +
                    quad * 2;
#pragma unroll
    for (int kk = 0; kk < 16; ++kk) {
      ull lo = __hip_atomic_load(hp + kk * 8, __ATOMIC_RELAXED,
                                 __HIP_MEMORY_SCOPE_AGENT);
      ull hi = __hip_atomic_load(hp + kk * 8 + 1, __ATOMIC_RELAXED,
                                 __HIP_MEMORY_SCOPE_AGENT);
      union { ull u2[2]; f16x8 v8; } cv;
      cv.u2[0] = lo; cv.u2[1] = hi;
      bfr[kk] = cv.v8;
    }
    classify(bfr, TT - 1);
  }
}

extern "C" void kernel_launch(void* const* d_in, const int* in_sizes, int n_in,
                              void* d_out, int out_size, void* d_ws,
                              size_t ws_size, hipStream_t stream) {
  const float* input = (const float*)d_in[0];
  const float* dtp = (const float*)d_in[1];
  const float* W_ih = (const float*)d_in[2];
  const float* W_hh = (const float*)d_in[3];
  const float* b_ih = (const float*)d_in[4];
  const float* b_hh = (const float*)d_in[5];
  const float* W_cls = (const float*)d_in[6];
  const float* b_cls = (const float*)d_in[7];
  float* out = (float*)d_out;

  // ws layout: [0, 16K): 1024 per-wave flags at 16B stride;
  //            [16K, 16K+512K): h double-buffer [2][16][16][512] f16
  uint32_t* flg = (uint32_t*)d_ws;
  f16* h_buf = (f16*)((char*)d_ws + 16384);
  const int nws_words = (16384 + 2 * 16 * 16 * HH * 2) / 4;  // 135168

  zero_ws<<<256, 256, 0, stream>>>(flg, nws_words);
  lstm_kernel<<<256, 256, 0, stream>>>(input, dtp, W_ih, W_hh, b_ih, b_hh,
                                       W_cls, b_cls, out, flg, h_buf);
}

// Round 7
// 1761.274 us; speedup vs baseline: 2.0843x; 2.0843x over previous
//
#include <hip/hip_runtime.h>
#include <stdint.h>

#define TT 512
#define BB 256
#define HH 512
#define NOUTC 64
// 16 groups x 16 blocks. R13 = R12 seqlock + BOUNDED retry (diagnostic
// fallback: a hidden protocol flaw now yields a finite wrong-answer run
// instead of a dead container). Group-slot stride 2048 ull (16KB) matches
// the publisher's 16*HH f16 (R12 fix; R10/R11's 1024 aliased groups ->
// deadlock). Flagless seqlock exchange: each published 8B word (4xf16 h)
// carries a sequence bit in bit0 of its low f16 (|h|<1, <=1 ulp).
// Consumers load h directly with per-word retry until the seq bit matches:
// no publisher drain, no flags, no separate poll, ONE barrier per step.

typedef _Float16 f16;
typedef f16 f16x8 __attribute__((ext_vector_type(8)));
typedef float f32x4 __attribute__((ext_vector_type(4)));
typedef unsigned long long ull;

__device__ __forceinline__ float sigmoidf_(float x) {
  x = fminf(fmaxf(x, -30.f), 30.f);
  return 1.f / (1.f + __expf(-x));
}
__device__ __forceinline__ float tanhf_(float x) {
  x = fminf(fmaxf(x, -15.f), 15.f);
  float e = __expf(2.f * x);
  return (e - 1.f) / (e + 1.f);
}

__device__ __forceinline__ f16x8 cvt8(const float* __restrict__ src) {
  float4 p0 = *(const float4*)(src);
  float4 p1 = *(const float4*)(src + 4);
  f16x8 a;
  a[0] = (f16)p0.x; a[1] = (f16)p0.y; a[2] = (f16)p0.z; a[3] = (f16)p0.w;
  a[4] = (f16)p1.x; a[5] = (f16)p1.y; a[6] = (f16)p1.z; a[7] = (f16)p1.w;
  return a;
}

__global__ void zero_ws(uint32_t* __restrict__ ws, int nws) {
  int idx = blockIdx.x * blockDim.x + threadIdx.x;
  int stride = gridDim.x * blockDim.x;
  for (int i = idx; i < nws; i += stride) ws[i] = 0u;
}

__global__ __launch_bounds__(256, 1) void lstm_kernel(
    const float* __restrict__ input, const float* __restrict__ dtp,
    const float* __restrict__ W_ih, const float* __restrict__ W_hh,
    const float* __restrict__ b_ih, const float* __restrict__ b_hh,
    const float* __restrict__ W_cls, const float* __restrict__ b_cls,
    float* __restrict__ out, f16* __restrict__ h_buf) {
  __shared__ __align__(16) f16 xh_h[2][16][520];  // h double-buffer (padded)
  __shared__ __align__(16) f16 xb[2][16][136];    // x double-buffer (padded)
  __shared__ __align__(16) f16x8 wlds[16][64];    // W_cls frags (cls blocks)

  const int tid = threadIdx.x;
  const int g = blockIdx.x & 15;   // group: batch slice [g*16, g*16+16)
  const int s = blockIdx.x >> 4;   // sub: hidden slice [s*32, s*32+32)
  const int b0 = g * 16;
  const int w = tid >> 6;          // wave id 0..3
  const int lane = tid & 63;
  const int l = lane & 15;
  const int quad = lane >> 4;
  const int mt_o = s & 3;
  const bool cls_block = (s < 4);
  const int hb = s * 32 + w * 8;   // wave's 8-hidden slice base

  // ---- A-fragments: m-tile0 rows = {i,f}x8h, m-tile1 = {g,o}x8h.
  // D mapping: m=quad*4+r -> gate m>>3, h = hb + (m&7); col n = l.
  f16x8 afrag[2][20];
#pragma unroll
  for (int mp = 0; mp < 2; ++mp) {
    const int grow = (mp * 2 + (l >> 3)) * HH + hb + (l & 7);
#pragma unroll
    for (int it = 0; it < 20; ++it) {
      const int kb = it * 32 + quad * 8;
      const float* src = (kb < 128) ? (W_ih + (size_t)grow * 128 + kb)
                                    : (W_hh + (size_t)grow * HH + (kb - 128));
      afrag[mp][it] = cvt8(src);
    }
  }

  // ---- gate biases (quad<2 lanes): h = hb + (quad&1)*4 + r
  float gb_i[4], gb_f[4], gb_g[4], gb_o[4];
  {
    const int hg = hb + (quad & 1) * 4;
#pragma unroll
    for (int r = 0; r < 4; ++r) {
      gb_i[r] = b_ih[0 * HH + hg + r] + b_hh[0 * HH + hg + r];
      gb_f[r] = b_ih[1 * HH + hg + r] + b_hh[1 * HH + hg + r];
      gb_g[r] = b_ih[2 * HH + hg + r] + b_hh[2 * HH + hg + r];
      gb_o[r] = b_ih[3 * HH + hg + r] + b_hh[3 * HH + hg + r];
    }
  }

  // ---- classifier state (wave0 of s<4 blocks)
  float bcls4[4] = {0.f, 0.f, 0.f, 0.f};
  if (cls_block && w == 0) {
#pragma unroll
    for (int r = 0; r < 4; ++r) bcls4[r] = b_cls[mt_o * 16 + quad * 4 + r];
#pragma unroll
    for (int it = 0; it < 16; ++it)
      wlds[it][lane] =
          cvt8(W_cls + (size_t)(mt_o * 16 + l) * HH + it * 32 + quad * 8);
  }

  auto classify = [&](int slot, int tt) {
    f32x4 oa = {0.f, 0.f, 0.f, 0.f}, ob = {0.f, 0.f, 0.f, 0.f};
#pragma unroll
    for (int it = 0; it < 16; it += 2) {
      f16x8 ba = *(const f16x8*)(&xh_h[slot][l][it * 32 + quad * 8]);
      f16x8 bb = *(const f16x8*)(&xh_h[slot][l][(it + 1) * 32 + quad * 8]);
      oa = __builtin_amdgcn_mfma_f32_16x16x32_f16(wlds[it][lane], ba, oa, 0, 0, 0);
      ob = __builtin_amdgcn_mfma_f32_16x16x32_f16(wlds[it + 1][lane], bb, ob, 0, 0, 0);
    }
    float4 o;
    o.x = oa[0] + ob[0] + bcls4[0];
    o.y = oa[1] + ob[1] + bcls4[1];
    o.z = oa[2] + ob[2] + bcls4[2];
    o.w = oa[3] + ob[3] + bcls4[3];
    *(float4*)(out + ((size_t)tt * BB + b0 + l) * NOUTC + mt_o * 16 +
               quad * 4) = o;
  };

  // stage h_{t_-1} (seq-checked) from h_buf slot (t_-1)&1 into xh_h[t_&1].
  // Group-slot stride: 16 batch x 512 h x 2B = 16KB = 2048 ull.
  // Bounded retry: after 2^16 spins a lane accepts the stale word — a
  // protocol flaw then shows as a finite failing run, not a dead container.
  auto stage_h = [&](int t_) {
    const uint32_t e = (uint32_t)((((t_ - 1) >> 1) & 1) ^ 1);
    const ull* hbp =
        (const ull*)h_buf + ((size_t)((t_ - 1) & 1) * 16 + g) * 2048;
    ull v[8];
#pragma unroll
    for (int ci = 0; ci < 8; ++ci)
      v[ci] = __hip_atomic_load(hbp + ci * 256 + tid, __ATOMIC_RELAXED,
                                __HIP_MEMORY_SCOPE_AGENT);
    for (int spin = 0; spin < (1 << 16); ++spin) {
      uint32_t stale = 0;
#pragma unroll
      for (int ci = 0; ci < 8; ++ci)
        if (((uint32_t)v[ci] ^ e) & 1u) stale |= 1u << ci;
      if (!stale) break;
      __builtin_amdgcn_s_sleep(1);
#pragma unroll
      for (int ci = 0; ci < 8; ++ci)
        if (stale & (1u << ci))
          v[ci] = __hip_atomic_load(hbp + ci * 256 + tid, __ATOMIC_RELAXED,
                                    __HIP_MEMORY_SCOPE_AGENT);
    }
#pragma unroll
    for (int ci = 0; ci < 8; ++ci) {
      const int c2 = ci * 256 + tid;
      *(ull*)(&xh_h[t_ & 1][c2 >> 7][(c2 & 127) * 4]) = v[ci];
    }
  };

  // ---- prologue: zero xh_h[0] (h_{-1} = 0), prefetch x_0
  {
    ull* zp = (ull*)&xh_h[0][0][0];  // 16*520 f16 = 2080 ull
    for (int i = tid; i < 2080; i += 256) zp[i] = 0ull;
  }
  const int kx = tid & 127;
  const int nx0 = tid >> 7;
  float xf[8];
#pragma unroll
  for (int ii = 0; ii < 8; ++ii) {
    const int row = b0 + ii * 2 + nx0;
    xf[ii] = (kx < 127) ? input[(size_t)row * 127 + kx] : dtp[row];
  }
  float cc[4] = {0.f, 0.f, 0.f, 0.f};

  for (int t = 0; t < TT; ++t) {
    // ---- stage h_{t-1} with seqlock retry (the load IS the poll)
    if (t > 0) stage_h(t);

    // ---- write x_t into its slot (prefetched last iteration)
#pragma unroll
    for (int ii = 0; ii < 8; ++ii) xb[t & 1][ii * 2 + nx0][kx] = (f16)xf[ii];

    __syncthreads();  // the ONE barrier: staging + x writes -> MFMA reads

    // ---- gates: [4 gates x 8 hid] x [16 batch], K = 640
    f32x4 acc0 = {0.f, 0.f, 0.f, 0.f}, acc1 = {0.f, 0.f, 0.f, 0.f};
    const int xs = t & 1;
#pragma unroll
    for (int it = 0; it < 4; ++it) {
      f16x8 b = *(const f16x8*)(&xb[xs][l][it * 32 + quad * 8]);
      acc0 = __builtin_amdgcn_mfma_f32_16x16x32_f16(afrag[0][it], b, acc0, 0, 0, 0);
      acc1 = __builtin_amdgcn_mfma_f32_16x16x32_f16(afrag[1][it], b, acc1, 0, 0, 0);
    }
#pragma unroll
    for (int kk = 0; kk < 16; ++kk) {
      f16x8 b = *(const f16x8*)(&xh_h[xs][l][kk * 32 + quad * 8]);
      acc0 = __builtin_amdgcn_mfma_f32_16x16x32_f16(afrag[0][4 + kk], b, acc0, 0, 0, 0);
      acc1 = __builtin_amdgcn_mfma_f32_16x16x32_f16(afrag[1][4 + kk], b, acc1, 0, 0, 0);
    }

    // ---- cell update in regs; f,o come from lane^32
    float fsh[4], osh[4];
#pragma unroll
    for (int r = 0; r < 4; ++r) {
      fsh[r] = __shfl_xor(acc0[r], 32, 64);
      osh[r] = __shfl_xor(acc1[r], 32, 64);
    }
    if (quad < 2) {
      union { f16 h4[4]; ull u; } pk;
#pragma unroll
      for (int r = 0; r < 4; ++r) {
        float vi = acc0[r] + gb_i[r];
        float vf = fsh[r] + gb_f[r];
        float vg = acc1[r] + gb_g[r];
        float vo = osh[r] + gb_o[r];
        float iv = sigmoidf_(vi), fv = sigmoidf_(vf);
        float gv = tanhf_(vg), ov = sigmoidf_(vo);
        cc[r] = fv * cc[r] + iv * gv;
        pk.h4[r] = (f16)(ov * tanhf_(cc[r]));
      }
      // force seq bit into bit0 of the low f16 (<=1 ulp, |h|<1)
      pk.u = (pk.u & ~1ull) | (ull)((((t >> 1) & 1) ^ 1));
      __hip_atomic_store(
          (ull*)(h_buf + ((size_t)(t & 1) * 16 + g) * (16 * HH) +
                 (size_t)l * HH + hb + quad * 4),
          pk.u, __ATOMIC_RELAXED, __HIP_MEMORY_SCOPE_AGENT);
    }
    // keep the publish above the next retry loop (livelock guard)
    asm volatile("" ::: "memory");

    // ---- prefetch x_{t+1} (latency hides under classify / next retry)
    if (t + 1 < TT) {
#pragma unroll
      for (int ii = 0; ii < 8; ++ii) {
        const int row = (t + 1) * BB + b0 + ii * 2 + nx0;
        xf[ii] = (kx < 127) ? input[(size_t)row * 127 + kx] : dtp[row];
      }
    }

    // ---- classifier out[t-1]: xh_h[t&1] stays valid until iter t+2
    if (t > 0 && cls_block && w == 0) classify(t & 1, t - 1);
  }

  // ---- tail: out[TT-1] from h_{TT-1} (cls blocks only)
  if (cls_block) {
    stage_h(TT);      // h_{TT-1} -> xh_h[0]
    __syncthreads();
    if (w == 0) classify(0, TT - 1);
  }
}

extern "C" void kernel_launch(void* const* d_in, const int* in_sizes, int n_in,
                              void* d_out, int out_size, void* d_ws,
                              size_t ws_size, hipStream_t stream) {
  const float* input = (const float*)d_in[0];
  const float* dtp = (const float*)d_in[1];
  const float* W_ih = (const float*)d_in[2];
  const float* W_hh = (const float*)d_in[3];
  const float* b_ih = (const float*)d_in[4];
  const float* b_hh = (const float*)d_in[5];
  const float* W_cls = (const float*)d_in[6];
  const float* b_cls = (const float*)d_in[7];
  float* out = (float*)d_out;

  // ws layout: [0, 512K): h double-buffer [2][16][16][512] f16.
  // Must be zeroed: seq bit0==0 reads as stale (expected bit is 1 for t=0,1).
  f16* h_buf = (f16*)d_ws;
  const int nws_words = (2 * 16 * 16 * HH * 2) / 4;  // 131072

  zero_ws<<<256, 256, 0, stream>>>((uint32_t*)d_ws, nws_words);
  lstm_kernel<<<256, 256, 0, stream>>>(input, dtp, W_ih, W_hh, b_ih, b_hh,
                                       W_cls, b_cls, out, h_buf);
}